// Round 1
// baseline (28.248 us; speedup 1.0000x reference)
//
#include <hip/hip_runtime.h>
#include <math.h>

// QNN forward: logits[b,c] = fc_b[c] + (sum_j wv[c][j] * |psi_j|^2) / ||x_b||^2
// psi = (U0 (x) U1 (x) U2 (x) U3) @ x_b   (CNOT row-permutation folded into wv)
//
// ws layout (floats):
//   [0..31]  gates: qubit q at ws+8q: {g00r,g00i,g01r,g01i,g10r,g10i,g11r,g11i}
//   [32..79] wv[3][16] (CNOT-permuted Z/fc_w contraction weights)
//   [80..82] fc_b

#define QNN_BATCH 1048576

__device__ __forceinline__ int qnn_cnot_perm(int k, int c, int t) {
    int cbit = 1 << (3 - c), tbit = 1 << (3 - t);
    return (k & cbit) ? (k ^ tbit) : k;
}

__global__ void qnn_setup(const float* __restrict__ params,
                          const float* __restrict__ fc_w,
                          const float* __restrict__ fc_b,
                          float* __restrict__ ws) {
    if (threadIdx.x != 0 || blockIdx.x != 0) return;
    // Per-qubit gate Ui = RZ @ RY @ RX
    for (int q = 0; q < 4; ++q) {
        float hx = 0.5f * params[q * 3 + 0];
        float hy = 0.5f * params[q * 3 + 1];
        float hz = 0.5f * params[q * 3 + 2];
        float cx = cosf(hx), sx = sinf(hx);
        float cy = cosf(hy), sy = sinf(hy);
        float cz = cosf(hz), sz = sinf(hz);
        float A = cy * cx, B = sy * sx, C = sy * cx, D = cy * sx;
        float* g = ws + q * 8;
        g[0] =  cz * A + sz * B;   // g00 re
        g[1] =  cz * B - sz * A;   // g00 im
        g[2] = -cz * C - sz * D;   // g01 re
        g[3] =  sz * C - cz * D;   // g01 im
        g[4] =  cz * C + sz * D;   // g10 re
        g[5] =  sz * C - cz * D;   // g10 im
        g[6] =  cz * A + sz * B;   // g11 re
        g[7] =  sz * A - cz * B;   // g11 im
    }
    // wv[c][q(o)] = sum_w fc_w[c,w] * zsign(o,w);  q = p01 o p12 o p23
    for (int o = 0; o < 16; ++o) {
        int j = qnn_cnot_perm(qnn_cnot_perm(qnn_cnot_perm(o, 2, 3), 1, 2), 0, 1);
        for (int c = 0; c < 3; ++c) {
            float s = 0.f;
            for (int w = 0; w < 4; ++w) {
                float z = 1.f - 2.f * (float)((o >> (3 - w)) & 1);
                s += fc_w[c * 4 + w] * z;
            }
            ws[32 + c * 16 + j] = s;
        }
    }
    for (int c = 0; c < 3; ++c) ws[80 + c] = fc_b[c];
}

// Complex butterfly stage with stride S (gate at G), in-place on yr/yi.
#define QNN_CSTAGE(S, G)                                                        \
    do {                                                                        \
        const float g00r=(G)[0], g00i=(G)[1], g01r=(G)[2], g01i=(G)[3];         \
        const float g10r=(G)[4], g10i=(G)[5], g11r=(G)[6], g11i=(G)[7];         \
        _Pragma("unroll")                                                       \
        for (int base = 0; base < 16; base += 2 * (S)) {                        \
            _Pragma("unroll")                                                   \
            for (int k = 0; k < (S); ++k) {                                     \
                const int j0 = base + k, j1 = j0 + (S);                         \
                const float ar = yr[j0], ai = yi[j0];                           \
                const float br = yr[j1], bi = yi[j1];                           \
                yr[j0] = fmaf(g00r, ar, fmaf(-g00i, ai, fmaf(g01r, br, -g01i * bi))); \
                yi[j0] = fmaf(g00r, ai, fmaf( g00i, ar, fmaf(g01r, bi,  g01i * br))); \
                yr[j1] = fmaf(g10r, ar, fmaf(-g10i, ai, fmaf(g11r, br, -g11i * bi))); \
                yi[j1] = fmaf(g10r, ai, fmaf( g10i, ar, fmaf(g11r, bi,  g11i * br))); \
            }                                                                   \
        }                                                                       \
    } while (0)

__global__ __launch_bounds__(256) void qnn_main(const float* __restrict__ x,
                                                const float* __restrict__ ws,
                                                float* __restrict__ out) {
    const int t = blockIdx.x * blockDim.x + threadIdx.x;
    if (t >= QNN_BATCH) return;

    const float4* xp = (const float4*)(x + (size_t)t * 16);
    float4 v0 = xp[0], v1 = xp[1], v2 = xp[2], v3 = xp[3];
    float xv[16] = {v0.x, v0.y, v0.z, v0.w, v1.x, v1.y, v1.z, v1.w,
                    v2.x, v2.y, v2.z, v2.w, v3.x, v3.y, v3.z, v3.w};

    float n2 = 0.f;
#pragma unroll
    for (int i = 0; i < 16; ++i) n2 = fmaf(xv[i], xv[i], n2);

    float yr[16], yi[16];
    // Stage qubit 0 (stride 8), real input.
    {
        const float g00r = ws[0], g00i = ws[1], g01r = ws[2], g01i = ws[3];
        const float g10r = ws[4], g10i = ws[5], g11r = ws[6], g11i = ws[7];
#pragma unroll
        for (int k = 0; k < 8; ++k) {
            const float a = xv[k], b = xv[k + 8];
            yr[k]     = fmaf(g00r, a, g01r * b);
            yi[k]     = fmaf(g00i, a, g01i * b);
            yr[k + 8] = fmaf(g10r, a, g11r * b);
            yi[k + 8] = fmaf(g10i, a, g11i * b);
        }
    }
    QNN_CSTAGE(4, ws + 8);   // qubit 1
    QNN_CSTAGE(2, ws + 16);  // qubit 2
    QNN_CSTAGE(1, ws + 24);  // qubit 3

    float acc0 = 0.f, acc1 = 0.f, acc2 = 0.f;
#pragma unroll
    for (int j = 0; j < 16; ++j) {
        const float p = fmaf(yr[j], yr[j], yi[j] * yi[j]);
        acc0 = fmaf(ws[32 + j], p, acc0);
        acc1 = fmaf(ws[48 + j], p, acc1);
        acc2 = fmaf(ws[64 + j], p, acc2);
    }
    const float inv = 1.0f / n2;
    float* o = out + (size_t)t * 3;
    o[0] = fmaf(acc0, inv, ws[80]);
    o[1] = fmaf(acc1, inv, ws[81]);
    o[2] = fmaf(acc2, inv, ws[82]);
}

extern "C" void kernel_launch(void* const* d_in, const int* in_sizes, int n_in,
                              void* d_out, int out_size, void* d_ws, size_t ws_size,
                              hipStream_t stream) {
    (void)in_sizes; (void)n_in; (void)out_size; (void)ws_size;
    const float* x      = (const float*)d_in[0];
    const float* params = (const float*)d_in[1];
    const float* fc_w   = (const float*)d_in[2];
    const float* fc_b   = (const float*)d_in[3];
    float* ws  = (float*)d_ws;
    float* out = (float*)d_out;

    qnn_setup<<<1, 64, 0, stream>>>(params, fc_w, fc_b, ws);
    qnn_main<<<QNN_BATCH / 256, 256, 0, stream>>>(x, ws, out);
}